// Round 1
// baseline (128.445 us; speedup 1.0000x reference)
//
#include <hip/hip_runtime.h>
#include <math.h>

#define L_SEQ 1024
#define DIMSZ 512
#define NH 8
#define ND 64
#define NB 2
#define CHUNK 64
#define NC (L_SEQ / CHUNK)   // 16
#define BHTOT (NB * NH)      // 16

// ---------------------------------------------------------------------------
// Kernel 1: QKV projections.  out[n,o] = sum_i x[n,i] * W[o,i] + b[o]
// 64x64 output tile per block, 256 threads, 4x4 per thread, BK=32.
// ---------------------------------------------------------------------------
__global__ __launch_bounds__(256) void proj_kernel(
    const float* __restrict__ x,
    const float* __restrict__ wq, const float* __restrict__ bq,
    const float* __restrict__ wk, const float* __restrict__ bk,
    const float* __restrict__ wv, const float* __restrict__ bv,
    float* __restrict__ qo, float* __restrict__ ko, float* __restrict__ vo)
{
    const float* w; const float* bias; float* out;
    if (blockIdx.z == 0)      { w = wq; bias = bq; out = qo; }
    else if (blockIdx.z == 1) { w = wk; bias = bk; out = ko; }
    else                      { w = wv; bias = bv; out = vo; }

    __shared__ float xs[64][33];
    __shared__ float wsh[64][33];
    const int tid = threadIdx.x;
    const int row0 = blockIdx.x * 64;
    const int col0 = blockIdx.y * 64;
    const int ty = tid >> 4, tx = tid & 15;

    float acc[4][4] = {};

    for (int k0 = 0; k0 < DIMSZ; k0 += 32) {
        for (int i = tid; i < 512; i += 256) {
            int r = i >> 3, c4 = (i & 7) << 2;
            const float4 xv = *(const float4*)(x + (size_t)(row0 + r) * DIMSZ + k0 + c4);
            xs[r][c4+0] = xv.x; xs[r][c4+1] = xv.y; xs[r][c4+2] = xv.z; xs[r][c4+3] = xv.w;
            const float4 wv4 = *(const float4*)(w + (size_t)(col0 + r) * DIMSZ + k0 + c4);
            wsh[r][c4+0] = wv4.x; wsh[r][c4+1] = wv4.y; wsh[r][c4+2] = wv4.z; wsh[r][c4+3] = wv4.w;
        }
        __syncthreads();
        #pragma unroll
        for (int kk = 0; kk < 32; ++kk) {
            float a[4], b[4];
            #pragma unroll
            for (int i = 0; i < 4; ++i) a[i] = xs[ty*4+i][kk];
            #pragma unroll
            for (int j = 0; j < 4; ++j) b[j] = wsh[tx*4+j][kk];
            #pragma unroll
            for (int i = 0; i < 4; ++i)
                #pragma unroll
                for (int j = 0; j < 4; ++j)
                    acc[i][j] = fmaf(a[i], b[j], acc[i][j]);
        }
        __syncthreads();
    }
    #pragma unroll
    for (int i = 0; i < 4; ++i) {
        const int r = row0 + ty*4 + i;
        #pragma unroll
        for (int j = 0; j < 4; ++j) {
            const int cidx = col0 + tx*4 + j;
            out[(size_t)r * DIMSZ + cidx] = acc[i][j] + bias[cidx];
        }
    }
}

// ---------------------------------------------------------------------------
// Kernel 2: prep.  theta[h,d] = atan2(im,re);  logamp[h] = log(sigmoid(a))
// ---------------------------------------------------------------------------
__global__ void prep_kernel(const float* __restrict__ ph_re, const float* __restrict__ ph_im,
                            const float* __restrict__ amplitude,
                            float* __restrict__ theta, float* __restrict__ logamp)
{
    const int tid = threadIdx.x;
    if (tid < NH * ND) theta[tid] = atan2f(ph_im[tid], ph_re[tid]);
    if (tid < NH) {
        float a = amplitude[tid];
        float amp = 1.0f / (1.0f + expf(-a));
        logamp[tid] = logf(amp);
    }
}

// ---------------------------------------------------------------------------
// Kernel 3: per-chunk decayed K^T V.
// KV_c[d,e] = sum_j lambda_d^{C-1-j} k[j,d] v[j,e]   (complex; k,v real)
// One block per (b,h,c).  256 threads; thread owns 16 d's for e=lane.
// ---------------------------------------------------------------------------
__global__ __launch_bounds__(256) void chunk_kv_kernel(
    const float* __restrict__ k, const float* __restrict__ v,
    const float* __restrict__ theta, const float* __restrict__ logamp,
    float2* __restrict__ kv)
{
    const int bhc = blockIdx.x;            // (b*NH+h)*NC + c
    const int c  = bhc & (NC - 1);
    const int bh = bhc >> 4;
    const int b = bh >> 3, h = bh & 7;
    const int tid = threadIdx.x;
    const int lane = tid & 63, grp = tid >> 6;

    __shared__ float ktr[CHUNK][ND + 1];
    __shared__ float kti[CHUNK][ND + 1];
    __shared__ float vs[CHUNK][ND + 1];

    const float th = theta[h*ND + lane];
    const float la = logamp[h];

    for (int jj = 0; jj < 16; ++jj) {
        const int j = grp*16 + jj;
        const int l = c*CHUNK + j;
        const size_t off = ((size_t)(b*L_SEQ + l)) * DIMSZ + h*ND + lane;
        const float kk = k[off];
        const float vv = v[off];
        const float p = (float)(CHUNK - 1 - j);
        const float ap = expf(la * p);
        float s, ct; sincosf(th * p, &s, &ct);
        ktr[j][lane] = kk * ap * ct;
        kti[j][lane] = kk * ap * s;
        vs[j][lane]  = vv;
    }
    __syncthreads();

    float accr[16], acci[16];
    #pragma unroll
    for (int dd = 0; dd < 16; ++dd) { accr[dd] = 0.f; acci[dd] = 0.f; }
    for (int j = 0; j < CHUNK; ++j) {
        const float vv = vs[j][lane];
        #pragma unroll
        for (int dd = 0; dd < 16; ++dd) {
            const int d = grp*16 + dd;
            accr[dd] = fmaf(ktr[j][d], vv, accr[dd]);
            acci[dd] = fmaf(kti[j][d], vv, acci[dd]);
        }
    }
    float2* dst = kv + (size_t)bhc * (ND*ND);
    #pragma unroll
    for (int dd = 0; dd < 16; ++dd) {
        const int d = grp*16 + dd;
        dst[d*ND + lane] = make_float2(accr[dd], acci[dd]);
    }
}

// ---------------------------------------------------------------------------
// Kernel 4: chunk-boundary state scan (element-parallel, in-place).
// Before: kvB[bh][c] = KV_c.   After: kvB[bh][c] = B_c (state BEFORE chunk c).
// B_0 = last_conv;  B_{c+1} = lambda^C * B_c + KV_c.
// ---------------------------------------------------------------------------
__global__ __launch_bounds__(256) void scan_kernel(
    float2* __restrict__ kvB,
    const float* __restrict__ lc_re, const float* __restrict__ lc_im,
    const float* __restrict__ theta, const float* __restrict__ logamp)
{
    const int gid = blockIdx.x * 256 + threadIdx.x;   // 65536
    const int bh = gid >> 12;            // / (D*D)
    const int idx = gid & 4095;
    const int h = bh & 7;
    const int d = idx >> 6;

    const float th = theta[h*ND + d];
    const float la = logamp[h];
    const float ampC = expf(la * (float)CHUNK);
    float s, ct; sincosf(th * (float)CHUNK, &s, &ct);
    const float aCr = ampC * ct, aCi = ampC * s;

    float Sr = lc_re[h*ND*ND + idx];
    float Si = lc_im[h*ND*ND + idx];

    float2* base = kvB + (size_t)bh * NC * (ND*ND) + idx;
    for (int c = 0; c < NC; ++c) {
        const float2 t = base[(size_t)c * (ND*ND)];
        base[(size_t)c * (ND*ND)] = make_float2(Sr, Si);
        const float nr = aCr*Sr - aCi*Si + t.x;
        const float ni = aCr*Si + aCi*Sr + t.y;
        Sr = nr; Si = ni;
    }
}

// ---------------------------------------------------------------------------
// Kernel 5: per-chunk output.
//  out[j,e] = Re( sum_d q[j,d] lam_d^{j+1} B_c[d,e] )                (cross)
//           + sum_{j'<=j} amp^{j-j'} (QR.KR^T + QI.KI^T)[j,j'] V[j',e] (intra)
// One block per (b,h,c); thread owns a 4x4 (j,e) tile.
// ---------------------------------------------------------------------------
__global__ __launch_bounds__(256) void chunk_out_kernel(
    const float* __restrict__ q, const float* __restrict__ k, const float* __restrict__ v,
    const float2* __restrict__ Bst,
    const float* __restrict__ theta, const float* __restrict__ logamp,
    float* __restrict__ out)
{
    const int bhc = blockIdx.x;
    const int c  = bhc & (NC - 1);
    const int bh = bhc >> 4;
    const int b = bh >> 3, h = bh & 7;
    const int tid = threadIdx.x;
    const int lane = tid & 63, grp = tid >> 6;
    const int ty = tid >> 4, tx = tid & 15;

    __shared__ float QR[CHUNK][ND + 1];
    __shared__ float QI[CHUNK][ND + 1];
    __shared__ float KR[CHUNK][ND + 1];
    __shared__ float KI[CHUNK][ND + 1];
    __shared__ float VS[CHUNK][ND + 1];
    __shared__ float cth[ND], sth[ND];

    const float la = logamp[h];
    {
        const float th = theta[h*ND + lane];
        if (tid < ND) { float s0, c0; sincosf(th, &s0, &c0); cth[tid] = c0; sth[tid] = s0; }
        for (int jj = 0; jj < 16; ++jj) {
            const int j = grp*16 + jj;
            const int l = c*CHUNK + j;
            const size_t off = ((size_t)(b*L_SEQ + l)) * DIMSZ + h*ND + lane;
            const float qq = q[off], kk = k[off], vv = v[off];
            float s, cc; sincosf(th * (float)j, &s, &cc);
            QR[j][lane] = qq * cc; QI[j][lane] = qq * s;
            KR[j][lane] = kk * cc; KI[j][lane] = kk * s;
            VS[j][lane] = vv;
        }
    }
    __syncthreads();

    float accO[4][4] = {};

    // ---- cross term: rows j = ty*4+i, cols e = tx*4+u ----
    float ampj1[4];
    #pragma unroll
    for (int i = 0; i < 4; ++i) ampj1[i] = expf(la * (float)(ty*4 + i + 1));
    const float2* Bbase = Bst + (size_t)bhc * (ND*ND);
    for (int d = 0; d < ND; ++d) {
        const float cd = cth[d], sd = sth[d];
        float2 Bv[4];
        #pragma unroll
        for (int u = 0; u < 4; ++u) Bv[u] = Bbase[d*ND + tx*4 + u];
        #pragma unroll
        for (int i = 0; i < 4; ++i) {
            const float qr = QR[ty*4+i][d], qi = QI[ty*4+i][d];
            const float qcr = (qr*cd - qi*sd) * ampj1[i];
            const float qci = (qr*sd + qi*cd) * ampj1[i];
            #pragma unroll
            for (int u = 0; u < 4; ++u)
                accO[i][u] = fmaf(qcr, Bv[u].x, fmaf(-qci, Bv[u].y, accO[i][u]));
        }
    }

    // ---- intra scores A[j,j'] ----
    float accA[4][4] = {};
    for (int d = 0; d < ND; ++d) {
        float qrv[4], qiv[4], krv[4], kiv[4];
        #pragma unroll
        for (int i = 0; i < 4; ++i) { qrv[i] = QR[ty*4+i][d]; qiv[i] = QI[ty*4+i][d]; }
        #pragma unroll
        for (int u = 0; u < 4; ++u) { krv[u] = KR[tx*4+u][d]; kiv[u] = KI[tx*4+u][d]; }
        #pragma unroll
        for (int i = 0; i < 4; ++i)
            #pragma unroll
            for (int u = 0; u < 4; ++u)
                accA[i][u] = fmaf(qrv[i], krv[u], fmaf(qiv[i], kiv[u], accA[i][u]));
    }
    __syncthreads();                      // everyone done reading KR
    float (*SA)[ND + 1] = KR;             // reuse KR's LDS for masked scores
    #pragma unroll
    for (int i = 0; i < 4; ++i) {
        const int j = ty*4 + i;
        #pragma unroll
        for (int u = 0; u < 4; ++u) {
            const int jp = tx*4 + u;
            const int delta = j - jp;
            SA[j][jp] = (delta >= 0) ? accA[i][u] * expf(la * (float)delta) : 0.0f;
        }
    }
    __syncthreads();

    // ---- PV: accO += A @ V ----
    for (int jp = 0; jp < CHUNK; ++jp) {
        float av[4], vv[4];
        #pragma unroll
        for (int i = 0; i < 4; ++i) av[i] = SA[ty*4+i][jp];
        #pragma unroll
        for (int u = 0; u < 4; ++u) vv[u] = VS[jp][tx*4+u];
        #pragma unroll
        for (int i = 0; i < 4; ++i)
            #pragma unroll
            for (int u = 0; u < 4; ++u)
                accO[i][u] = fmaf(av[i], vv[u], accO[i][u]);
    }

    #pragma unroll
    for (int i = 0; i < 4; ++i) {
        const int l = c*CHUNK + ty*4 + i;
        const size_t off = ((size_t)(b*L_SEQ + l)) * DIMSZ + h*ND + tx*4;
        *(float4*)(out + off) = make_float4(accO[i][0], accO[i][1], accO[i][2], accO[i][3]);
    }
}

// ---------------------------------------------------------------------------
extern "C" void kernel_launch(void* const* d_in, const int* in_sizes, int n_in,
                              void* d_out, int out_size, void* d_ws, size_t ws_size,
                              hipStream_t stream)
{
    const float* x     = (const float*)d_in[0];
    const float* wq_w  = (const float*)d_in[1];
    const float* wq_b  = (const float*)d_in[2];
    const float* wk_w  = (const float*)d_in[3];
    const float* wk_b  = (const float*)d_in[4];
    const float* wv_w  = (const float*)d_in[5];
    const float* wv_b  = (const float*)d_in[6];
    const float* ph_re = (const float*)d_in[7];
    const float* ph_im = (const float*)d_in[8];
    const float* ampl  = (const float*)d_in[9];
    const float* lc_re = (const float*)d_in[10];
    const float* lc_im = (const float*)d_in[11];
    float* out = (float*)d_out;

    float* wsf = (float*)d_ws;
    const size_t qkv_sz = (size_t)NB * L_SEQ * DIMSZ;   // 1,048,576 floats each
    float* q = wsf;
    float* k = q + qkv_sz;
    float* v = k + qkv_sz;
    float* theta  = v + qkv_sz;          // 512 floats
    float* logamp = theta + NH*ND;       // 8 floats (pad to 64)
    float2* kvB = (float2*)(logamp + 64);  // BHTOT*NC*ND*ND float2 = 8 MB

    proj_kernel<<<dim3(NB*L_SEQ/64, DIMSZ/64, 3), 256, 0, stream>>>(
        x, wq_w, wq_b, wk_w, wk_b, wv_w, wv_b, q, k, v);
    prep_kernel<<<1, 512, 0, stream>>>(ph_re, ph_im, ampl, theta, logamp);
    chunk_kv_kernel<<<BHTOT*NC, 256, 0, stream>>>(k, v, theta, logamp, kvB);
    scan_kernel<<<(BHTOT*ND*ND)/256, 256, 0, stream>>>(kvB, lc_re, lc_im, theta, logamp);
    chunk_out_kernel<<<BHTOT*NC, 256, 0, stream>>>(q, k, v, kvB, theta, logamp, out);
}

// Round 2
// 91.663 us; speedup vs baseline: 1.4013x; 1.4013x over previous
//
#include <hip/hip_runtime.h>
#include <hip/hip_bf16.h>
#include <math.h>

#define L_SEQ 1024
#define DIMSZ 512
#define NH 8
#define ND 64
#define NB 2
#define CHUNK 64
#define NC (L_SEQ / CHUNK)   // 16
#define BHTOT (NB * NH)      // 16
#define MTOT 2048
#define NTOT 1536
#define KEFF 1536

typedef __attribute__((ext_vector_type(8))) short bf16x8;
typedef __attribute__((ext_vector_type(4))) float f32x4;

#define GLD16(g, l) __builtin_amdgcn_global_load_lds( \
    (const __attribute__((address_space(1))) unsigned int*)(g), \
    (__attribute__((address_space(3))) unsigned int*)(l), 16, 0, 0)

__device__ static inline unsigned short bf16_hi(float f) {
    union { float f; unsigned u; } x; x.f = f;
    unsigned lsb = (x.u >> 16) & 1u;
    unsigned rounded = x.u + 0x7fffu + lsb;
    return (unsigned short)(rounded >> 16);
}
__device__ static inline float bf16_f(unsigned short h) {
    union { float f; unsigned u; } x; x.u = ((unsigned)h) << 16;
    return x.f;
}

// ---------------------------------------------------------------------------
// pack_x: A' = [x_hi | x_lo | x_hi]  (2048 x 1536 bf16)
// ---------------------------------------------------------------------------
__global__ __launch_bounds__(256) void pack_x_kernel(
    const float* __restrict__ x, unsigned short* __restrict__ A)
{
    const int i = blockIdx.x * 256 + threadIdx.x;    // 0..262143
    const int n  = i >> 7;
    const int kq = (i & 127) << 2;
    const float4 xv = *(const float4*)(x + (size_t)n * DIMSZ + kq);
    const float fa[4] = {xv.x, xv.y, xv.z, xv.w};
    unsigned short hv[4], lv[4];
    #pragma unroll
    for (int j = 0; j < 4; ++j) {
        hv[j] = bf16_hi(fa[j]);
        lv[j] = bf16_hi(fa[j] - bf16_f(hv[j]));
    }
    unsigned short* row = A + (size_t)n * KEFF;
    *(ushort4*)(row + kq)        = make_ushort4(hv[0], hv[1], hv[2], hv[3]);
    *(ushort4*)(row + 512 + kq)  = make_ushort4(lv[0], lv[1], lv[2], lv[3]);
    *(ushort4*)(row + 1024 + kq) = make_ushort4(hv[0], hv[1], hv[2], hv[3]);
}

// ---------------------------------------------------------------------------
// pack_w: B' rows o' = which*512+o :  [W_hi | W_hi | W_lo]  (1536 x 1536 bf16)
// ---------------------------------------------------------------------------
__global__ __launch_bounds__(256) void pack_w_kernel(
    const float* __restrict__ wq, const float* __restrict__ wk,
    const float* __restrict__ wv, unsigned short* __restrict__ Bm)
{
    const int which = blockIdx.y;
    const float* w = which == 0 ? wq : (which == 1 ? wk : wv);
    const int i = blockIdx.x * 256 + threadIdx.x;    // 0..65535
    const int o  = i >> 7;
    const int kq = (i & 127) << 2;
    const float4 wv4 = *(const float4*)(w + (size_t)o * DIMSZ + kq);
    const float fa[4] = {wv4.x, wv4.y, wv4.z, wv4.w};
    unsigned short hv[4], lv[4];
    #pragma unroll
    for (int j = 0; j < 4; ++j) {
        hv[j] = bf16_hi(fa[j]);
        lv[j] = bf16_hi(fa[j] - bf16_f(hv[j]));
    }
    unsigned short* row = Bm + (size_t)(which * 512 + o) * KEFF;
    *(ushort4*)(row + kq)        = make_ushort4(hv[0], hv[1], hv[2], hv[3]);
    *(ushort4*)(row + 512 + kq)  = make_ushort4(hv[0], hv[1], hv[2], hv[3]);
    *(ushort4*)(row + 1024 + kq) = make_ushort4(lv[0], lv[1], lv[2], lv[3]);
}

// ---------------------------------------------------------------------------
// GEMM: C[2048 x 1536] = A'[2048 x 1536] x B'^T, MFMA 16x16x32 bf16.
// 128x128 tile, BK=64, 4 waves (2x2), double-buffered global_load_lds with
// both-sides XOR swizzle (byte ^= (row&7)<<4 within 128B rows).
// ---------------------------------------------------------------------------
__global__ __launch_bounds__(256) void gemm_kernel(
    const unsigned short* __restrict__ A, const unsigned short* __restrict__ Bm,
    const float* __restrict__ bq, const float* __restrict__ bk, const float* __restrict__ bv,
    float* __restrict__ qo, float* __restrict__ ko, float* __restrict__ vo)
{
    __shared__ __align__(16) char lds[2][32768];   // [A 16KB | B 16KB] x 2
    const int tid  = threadIdx.x;
    const int lane = tid & 63;
    const int wave = tid >> 6;
    const int row0 = blockIdx.x * 128;
    const int col0 = blockIdx.y * 128;
    const int wr = wave >> 1, wc = wave & 1;

    // --- staging address precompute (inverse-swizzled global source) ---
    const int srow = tid >> 3;                // 0..31 (row within 32-row call)
    const int sin  = (tid & 7) << 4;          // byte within 128B row
    size_t goffA[4], goffB[4];
    #pragma unroll
    for (int c = 0; c < 4; ++c) {
        const int row = c * 32 + srow;
        const int swz = sin ^ ((row & 7) << 4);
        goffA[c] = (size_t)(row0 + row) * (KEFF * 2) + swz;
        goffB[c] = (size_t)(col0 + row) * (KEFF * 2) + swz;
    }
    const int ldst = tid * 16;
    const char* Abyte = (const char*)A;
    const char* Bbyte = (const char*)Bm;

    f32x4 acc[4][4];
    const f32x4 zf = {0.f, 0.f, 0.f, 0.f};
    #pragma unroll
    for (int m = 0; m < 4; ++m)
        #pragma unroll
        for (int n = 0; n < 4; ++n) acc[m][n] = zf;

    auto stage = [&](int buf, int t) {
        char* la = &lds[buf][0];
        char* lb = &lds[buf][16384];
        const size_t kb = (size_t)t * 128;
        #pragma unroll
        for (int c = 0; c < 4; ++c)
            GLD16(Abyte + goffA[c] + kb, la + c * 4096 + ldst);
        #pragma unroll
        for (int c = 0; c < 4; ++c)
            GLD16(Bbyte + goffB[c] + kb, lb + c * 4096 + ldst);
    };

    const int rl = lane & 15;
    const int kg = lane >> 4;
    const int rswz = (rl & 7) << 4;

    auto compute = [&](int buf) {
        const char* la = &lds[buf][0];
        const char* lb = &lds[buf][16384];
        #pragma unroll
        for (int ks = 0; ks < 2; ++ks) {
            bf16x8 av[4], bvv[4];
            #pragma unroll
            for (int m = 0; m < 4; ++m) {
                const int row = wr * 64 + m * 16 + rl;
                const int addr = (row * 128 + ks * 64 + kg * 16) ^ rswz;
                av[m] = *(const bf16x8*)(la + addr);
            }
            #pragma unroll
            for (int n = 0; n < 4; ++n) {
                const int row = wc * 64 + n * 16 + rl;
                const int addr = (row * 128 + ks * 64 + kg * 16) ^ rswz;
                bvv[n] = *(const bf16x8*)(lb + addr);
            }
            #pragma unroll
            for (int m = 0; m < 4; ++m)
                #pragma unroll
                for (int n = 0; n < 4; ++n)
                    acc[m][n] = __builtin_amdgcn_mfma_f32_16x16x32_bf16(
                        av[m], bvv[n], acc[m][n], 0, 0, 0);
        }
    };

    stage(0, 0);
    __syncthreads();
    const int NT = KEFF / 64;   // 24
    for (int t = 0; t < NT; ++t) {
        if (t + 1 < NT) stage((t + 1) & 1, t + 1);
        compute(t & 1);
        __syncthreads();
    }

    // --- epilogue: bias + store ---
    const int which = col0 >> 9;
    const float* bias = which == 0 ? bq : (which == 1 ? bk : bv);
    float* outp = which == 0 ? qo : (which == 1 ? ko : vo);
    const int colb = (col0 & 511) + wc * 64;
    #pragma unroll
    for (int n = 0; n < 4; ++n) {
        const int cl = colb + n * 16 + rl;
        const float bs = bias[cl];
        #pragma unroll
        for (int m = 0; m < 4; ++m) {
            const int rb = row0 + wr * 64 + m * 16 + kg * 4;
            #pragma unroll
            for (int r = 0; r < 4; ++r)
                outp[(size_t)(rb + r) * DIMSZ + cl] = acc[m][n][r] + bs;
        }
    }
}

// ---------------------------------------------------------------------------
// prep: theta[h,d] = atan2(im,re);  logamp[h] = log(sigmoid(a))
// ---------------------------------------------------------------------------
__global__ void prep_kernel(const float* __restrict__ ph_re, const float* __restrict__ ph_im,
                            const float* __restrict__ amplitude,
                            float* __restrict__ theta, float* __restrict__ logamp)
{
    const int tid = threadIdx.x;
    if (tid < NH * ND) theta[tid] = atan2f(ph_im[tid], ph_re[tid]);
    if (tid < NH) {
        float a = amplitude[tid];
        float amp = 1.0f / (1.0f + expf(-a));
        logamp[tid] = logf(amp);
    }
}

// ---------------------------------------------------------------------------
// chunk_kv: KV_c[d,e] = sum_j lambda_d^{C-1-j} k[j,d] v[j,e]
// ---------------------------------------------------------------------------
__global__ __launch_bounds__(256) void chunk_kv_kernel(
    const float* __restrict__ k, const float* __restrict__ v,
    const float* __restrict__ theta, const float* __restrict__ logamp,
    float2* __restrict__ kv)
{
    const int bhc = blockIdx.x;
    const int c  = bhc & (NC - 1);
    const int bh = bhc >> 4;
    const int b = bh >> 3, h = bh & 7;
    const int tid = threadIdx.x;
    const int lane = tid & 63, grp = tid >> 6;

    __shared__ float ktr[CHUNK][ND + 1];
    __shared__ float kti[CHUNK][ND + 1];
    __shared__ float vs[CHUNK][ND + 1];

    const float th = theta[h*ND + lane];
    const float la = logamp[h];

    for (int jj = 0; jj < 16; ++jj) {
        const int j = grp*16 + jj;
        const int l = c*CHUNK + j;
        const size_t off = ((size_t)(b*L_SEQ + l)) * DIMSZ + h*ND + lane;
        const float kk = k[off];
        const float vv = v[off];
        const float p = (float)(CHUNK - 1 - j);
        const float ap = expf(la * p);
        float s, ct; sincosf(th * p, &s, &ct);
        ktr[j][lane] = kk * ap * ct;
        kti[j][lane] = kk * ap * s;
        vs[j][lane]  = vv;
    }
    __syncthreads();

    float accr[16], acci[16];
    #pragma unroll
    for (int dd = 0; dd < 16; ++dd) { accr[dd] = 0.f; acci[dd] = 0.f; }
    for (int j = 0; j < CHUNK; ++j) {
        const float vv = vs[j][lane];
        #pragma unroll
        for (int dd = 0; dd < 16; ++dd) {
            const int d = grp*16 + dd;
            accr[dd] = fmaf(ktr[j][d], vv, accr[dd]);
            acci[dd] = fmaf(kti[j][d], vv, acci[dd]);
        }
    }
    float2* dst = kv + (size_t)bhc * (ND*ND);
    #pragma unroll
    for (int dd = 0; dd < 16; ++dd) {
        const int d = grp*16 + dd;
        dst[d*ND + lane] = make_float2(accr[dd], acci[dd]);
    }
}

// ---------------------------------------------------------------------------
// scan: kvB[bh][c] := state BEFORE chunk c.  B_0 = last_conv.
// ---------------------------------------------------------------------------
__global__ __launch_bounds__(256) void scan_kernel(
    float2* __restrict__ kvB,
    const float* __restrict__ lc_re, const float* __restrict__ lc_im,
    const float* __restrict__ theta, const float* __restrict__ logamp)
{
    const int gid = blockIdx.x * 256 + threadIdx.x;   // 65536
    const int bh = gid >> 12;
    const int idx = gid & 4095;
    const int h = bh & 7;
    const int d = idx >> 6;

    const float th = theta[h*ND + d];
    const float la = logamp[h];
    const float ampC = expf(la * (float)CHUNK);
    float s, ct; sincosf(th * (float)CHUNK, &s, &ct);
    const float aCr = ampC * ct, aCi = ampC * s;

    float Sr = lc_re[h*ND*ND + idx];
    float Si = lc_im[h*ND*ND + idx];

    float2* base = kvB + (size_t)bh * NC * (ND*ND) + idx;
    for (int c = 0; c < NC; ++c) {
        const float2 t = base[(size_t)c * (ND*ND)];
        base[(size_t)c * (ND*ND)] = make_float2(Sr, Si);
        const float nr = aCr*Sr - aCi*Si + t.x;
        const float ni = aCr*Si + aCi*Sr + t.y;
        Sr = nr; Si = ni;
    }
}

// ---------------------------------------------------------------------------
// chunk_out: cross term + masked intra-chunk attention.
// ---------------------------------------------------------------------------
__global__ __launch_bounds__(256) void chunk_out_kernel(
    const float* __restrict__ q, const float* __restrict__ k, const float* __restrict__ v,
    const float2* __restrict__ Bst,
    const float* __restrict__ theta, const float* __restrict__ logamp,
    float* __restrict__ out)
{
    const int bhc = blockIdx.x;
    const int c  = bhc & (NC - 1);
    const int bh = bhc >> 4;
    const int b = bh >> 3, h = bh & 7;
    const int tid = threadIdx.x;
    const int lane = tid & 63, grp = tid >> 6;
    const int ty = tid >> 4, tx = tid & 15;

    __shared__ float QR[CHUNK][ND + 1];
    __shared__ float QI[CHUNK][ND + 1];
    __shared__ float KR[CHUNK][ND + 1];
    __shared__ float KI[CHUNK][ND + 1];
    __shared__ float VS[CHUNK][ND + 1];
    __shared__ float cth[ND], sth[ND];

    const float la = logamp[h];
    {
        const float th = theta[h*ND + lane];
        if (tid < ND) { float s0, c0; sincosf(th, &s0, &c0); cth[tid] = c0; sth[tid] = s0; }
        for (int jj = 0; jj < 16; ++jj) {
            const int j = grp*16 + jj;
            const int l = c*CHUNK + j;
            const size_t off = ((size_t)(b*L_SEQ + l)) * DIMSZ + h*ND + lane;
            const float qq = q[off], kk = k[off], vv = v[off];
            float s, cc; sincosf(th * (float)j, &s, &cc);
            QR[j][lane] = qq * cc; QI[j][lane] = qq * s;
            KR[j][lane] = kk * cc; KI[j][lane] = kk * s;
            VS[j][lane] = vv;
        }
    }
    __syncthreads();

    float accO[4][4] = {};

    float ampj1[4];
    #pragma unroll
    for (int i = 0; i < 4; ++i) ampj1[i] = expf(la * (float)(ty*4 + i + 1));
    const float2* Bbase = Bst + (size_t)bhc * (ND*ND);
    for (int d = 0; d < ND; ++d) {
        const float cd = cth[d], sd = sth[d];
        float2 Bv[4];
        #pragma unroll
        for (int u = 0; u < 4; ++u) Bv[u] = Bbase[d*ND + tx*4 + u];
        #pragma unroll
        for (int i = 0; i < 4; ++i) {
            const float qr = QR[ty*4+i][d], qi = QI[ty*4+i][d];
            const float qcr = (qr*cd - qi*sd) * ampj1[i];
            const float qci = (qr*sd + qi*cd) * ampj1[i];
            #pragma unroll
            for (int u = 0; u < 4; ++u)
                accO[i][u] = fmaf(qcr, Bv[u].x, fmaf(-qci, Bv[u].y, accO[i][u]));
        }
    }

    float accA[4][4] = {};
    for (int d = 0; d < ND; ++d) {
        float qrv[4], qiv[4], krv[4], kiv[4];
        #pragma unroll
        for (int i = 0; i < 4; ++i) { qrv[i] = QR[ty*4+i][d]; qiv[i] = QI[ty*4+i][d]; }
        #pragma unroll
        for (int u = 0; u < 4; ++u) { krv[u] = KR[tx*4+u][d]; kiv[u] = KI[tx*4+u][d]; }
        #pragma unroll
        for (int i = 0; i < 4; ++i)
            #pragma unroll
            for (int u = 0; u < 4; ++u)
                accA[i][u] = fmaf(qrv[i], krv[u], fmaf(qiv[i], kiv[u], accA[i][u]));
    }
    __syncthreads();
    float (*SA)[ND + 1] = KR;
    #pragma unroll
    for (int i = 0; i < 4; ++i) {
        const int j = ty*4 + i;
        #pragma unroll
        for (int u = 0; u < 4; ++u) {
            const int jp = tx*4 + u;
            const int delta = j - jp;
            SA[j][jp] = (delta >= 0) ? accA[i][u] * expf(la * (float)delta) : 0.0f;
        }
    }
    __syncthreads();

    for (int jp = 0; jp < CHUNK; ++jp) {
        float av[4], vv[4];
        #pragma unroll
        for (int i = 0; i < 4; ++i) av[i] = SA[ty*4+i][jp];
        #pragma unroll
        for (int u = 0; u < 4; ++u) vv[u] = VS[jp][tx*4+u];
        #pragma unroll
        for (int i = 0; i < 4; ++i)
            #pragma unroll
            for (int u = 0; u < 4; ++u)
                accO[i][u] = fmaf(av[i], vv[u], accO[i][u]);
    }

    #pragma unroll
    for (int i = 0; i < 4; ++i) {
        const int l = c*CHUNK + ty*4 + i;
        const size_t off = ((size_t)(b*L_SEQ + l)) * DIMSZ + h*ND + tx*4;
        *(float4*)(out + off) = make_float4(accO[i][0], accO[i][1], accO[i][2], accO[i][3]);
    }
}

// ---------------------------------------------------------------------------
extern "C" void kernel_launch(void* const* d_in, const int* in_sizes, int n_in,
                              void* d_out, int out_size, void* d_ws, size_t ws_size,
                              hipStream_t stream)
{
    const float* x     = (const float*)d_in[0];
    const float* wq_w  = (const float*)d_in[1];
    const float* wq_b  = (const float*)d_in[2];
    const float* wk_w  = (const float*)d_in[3];
    const float* wk_b  = (const float*)d_in[4];
    const float* wv_w  = (const float*)d_in[5];
    const float* wv_b  = (const float*)d_in[6];
    const float* ph_re = (const float*)d_in[7];
    const float* ph_im = (const float*)d_in[8];
    const float* ampl  = (const float*)d_in[9];
    const float* lc_re = (const float*)d_in[10];
    const float* lc_im = (const float*)d_in[11];
    float* out = (float*)d_out;

    float* wsf = (float*)d_ws;
    const size_t qkv_sz = (size_t)NB * L_SEQ * DIMSZ;       // 1,048,576 floats
    float* q = wsf;
    float* k = q + qkv_sz;
    float* v = k + qkv_sz;
    float* theta  = v + qkv_sz;                              // 512 floats
    float* logamp = theta + 512;                             // 512 floats (pad)
    unsigned short* Apk = (unsigned short*)(logamp + 512);   // 2048*1536 bf16 = 6MB
    float2* kvB = (float2*)(Apk + (size_t)MTOT * KEFF);      // 8MB
    unsigned short* Bpk = (unsigned short*)kvB;              // alias (4.7MB<8MB, dead before chunk_kv)

    pack_x_kernel<<<(MTOT * DIMSZ / 4) / 256, 256, 0, stream>>>(x, Apk);
    pack_w_kernel<<<dim3((DIMSZ * DIMSZ / 4) / 256, 3), 256, 0, stream>>>(wq_w, wk_w, wv_w, Bpk);
    prep_kernel<<<1, 512, 0, stream>>>(ph_re, ph_im, ampl, theta, logamp);
    gemm_kernel<<<dim3(MTOT / 128, NTOT / 128), 256, 0, stream>>>(
        Apk, Bpk, wq_b, wk_b, wv_b, q, k, v);
    chunk_kv_kernel<<<BHTOT * NC, 256, 0, stream>>>(k, v, theta, logamp, kvB);
    scan_kernel<<<(BHTOT * ND * ND) / 256, 256, 0, stream>>>(kvB, lc_re, lc_im, theta, logamp);
    chunk_out_kernel<<<BHTOT * NC, 256, 0, stream>>>(q, k, v, kvB, theta, logamp, out);
}

// Round 3
// 86.341 us; speedup vs baseline: 1.4876x; 1.0616x over previous
//
#include <hip/hip_runtime.h>
#include <hip/hip_bf16.h>
#include <math.h>

#define L_SEQ 1024
#define DIMSZ 512
#define NH 8
#define ND 64
#define NB 2
#define CHUNK 64
#define NC (L_SEQ / CHUNK)   // 16
#define BHTOT (NB * NH)      // 16
#define MTOT 2048
#define NTOT 1536
#define KEFF 1536
#define BM 128
#define BN 96

typedef __attribute__((ext_vector_type(8))) short bf16x8;
typedef __attribute__((ext_vector_type(4))) float f32x4;

#define GLD16(g, l) __builtin_amdgcn_global_load_lds( \
    (const __attribute__((address_space(1))) unsigned int*)(g), \
    (__attribute__((address_space(3))) unsigned int*)(l), 16, 0, 0)

__device__ static inline unsigned short bf16_hi(float f) {
    union { float f; unsigned u; } x; x.f = f;
    unsigned lsb = (x.u >> 16) & 1u;
    unsigned rounded = x.u + 0x7fffu + lsb;
    return (unsigned short)(rounded >> 16);
}
__device__ static inline float bf16_f(unsigned short h) {
    union { float f; unsigned u; } x; x.u = ((unsigned)h) << 16;
    return x.f;
}

// ---------------------------------------------------------------------------
// pack_all: blocks [0,1024): A' = [x_hi | x_lo | x_hi]
//           blocks [1024,1792): B' rows which*512+o = [W_hi | W_hi | W_lo]
//           block 1792: prep (theta, logamp)
// ---------------------------------------------------------------------------
__global__ __launch_bounds__(256) void pack_all_kernel(
    const float* __restrict__ x,
    const float* __restrict__ wq, const float* __restrict__ wk, const float* __restrict__ wv,
    const float* __restrict__ ph_re, const float* __restrict__ ph_im,
    const float* __restrict__ amplitude,
    unsigned short* __restrict__ A, unsigned short* __restrict__ Bm,
    float* __restrict__ theta, float* __restrict__ logamp)
{
    const int bid = blockIdx.x;
    const int tid = threadIdx.x;
    if (bid < 1024) {
        const int i = bid * 256 + tid;
        const int n  = i >> 7;
        const int kq = (i & 127) << 2;
        const float4 xv = *(const float4*)(x + (size_t)n * DIMSZ + kq);
        const float fa[4] = {xv.x, xv.y, xv.z, xv.w};
        unsigned short hv[4], lv[4];
        #pragma unroll
        for (int j = 0; j < 4; ++j) {
            hv[j] = bf16_hi(fa[j]);
            lv[j] = bf16_hi(fa[j] - bf16_f(hv[j]));
        }
        unsigned short* row = A + (size_t)n * KEFF;
        *(ushort4*)(row + kq)        = make_ushort4(hv[0], hv[1], hv[2], hv[3]);
        *(ushort4*)(row + 512 + kq)  = make_ushort4(lv[0], lv[1], lv[2], lv[3]);
        *(ushort4*)(row + 1024 + kq) = make_ushort4(hv[0], hv[1], hv[2], hv[3]);
    } else if (bid < 1792) {
        const int idx = bid - 1024;
        const int which = idx >> 8;
        const float* w = which == 0 ? wq : (which == 1 ? wk : wv);
        const int i = (idx & 255) * 256 + tid;
        const int o  = i >> 7;
        const int kq = (i & 127) << 2;
        const float4 wv4 = *(const float4*)(w + (size_t)o * DIMSZ + kq);
        const float fa[4] = {wv4.x, wv4.y, wv4.z, wv4.w};
        unsigned short hv[4], lv[4];
        #pragma unroll
        for (int j = 0; j < 4; ++j) {
            hv[j] = bf16_hi(fa[j]);
            lv[j] = bf16_hi(fa[j] - bf16_f(hv[j]));
        }
        unsigned short* row = Bm + (size_t)(which * 512 + o) * KEFF;
        *(ushort4*)(row + kq)        = make_ushort4(hv[0], hv[1], hv[2], hv[3]);
        *(ushort4*)(row + 512 + kq)  = make_ushort4(hv[0], hv[1], hv[2], hv[3]);
        *(ushort4*)(row + 1024 + kq) = make_ushort4(lv[0], lv[1], lv[2], lv[3]);
    } else {
        for (int t0 = tid; t0 < NH * ND; t0 += 256)
            theta[t0] = atan2f(ph_im[t0], ph_re[t0]);
        if (tid < NH) {
            float a = amplitude[tid];
            float amp = 1.0f / (1.0f + expf(-a));
            logamp[tid] = logf(amp);
        }
    }
}

// ---------------------------------------------------------------------------
// GEMM: C[2048 x 1536] = A' x B'^T, MFMA 16x16x32 bf16.
// 128x96 tile, BK=64, 4 waves (2x2, wave tile 64x48), double-buffered
// global_load_lds with both-sides XOR swizzle. Grid 16x16 = 256 = #CUs.
// ---------------------------------------------------------------------------
__global__ __launch_bounds__(256) void gemm_kernel(
    const unsigned short* __restrict__ A, const unsigned short* __restrict__ Bm,
    const float* __restrict__ bq, const float* __restrict__ bk, const float* __restrict__ bv,
    float* __restrict__ qo, float* __restrict__ ko, float* __restrict__ vo)
{
    __shared__ __align__(16) char lds[2][28672];   // [A 16KB | B 12KB] x 2
    const int tid  = threadIdx.x;
    const int lane = tid & 63;
    const int wave = tid >> 6;

    // XCD-aware swizzle: 256 blocks, 8 XCDs -> each XCD gets 2 row-panels.
    const int bid = blockIdx.y * 16 + blockIdx.x;
    const int sw  = (bid & 7) * 32 + (bid >> 3);
    const int row0 = (sw >> 4) * BM;
    const int col0 = (sw & 15) * BN;
    const int wr = wave >> 1, wc = wave & 1;

    const int srow = tid >> 3;                // 0..31
    const int sin  = (tid & 7) << 4;          // byte within 128B row
    size_t goffA[4], goffB[3];
    #pragma unroll
    for (int c = 0; c < 4; ++c) {
        const int row = c * 32 + srow;
        const int swz = sin ^ ((row & 7) << 4);
        goffA[c] = (size_t)(row0 + row) * (KEFF * 2) + swz;
    }
    #pragma unroll
    for (int c = 0; c < 3; ++c) {
        const int row = c * 32 + srow;
        const int swz = sin ^ ((row & 7) << 4);
        goffB[c] = (size_t)(col0 + row) * (KEFF * 2) + swz;
    }
    const int ldst = tid * 16;
    const char* Abyte = (const char*)A;
    const char* Bbyte = (const char*)Bm;

    f32x4 acc[4][3];
    const f32x4 zf = {0.f, 0.f, 0.f, 0.f};
    #pragma unroll
    for (int m = 0; m < 4; ++m)
        #pragma unroll
        for (int n = 0; n < 3; ++n) acc[m][n] = zf;

    auto stage = [&](int buf, int t) {
        char* la = &lds[buf][0];
        char* lb = &lds[buf][16384];
        const size_t kb = (size_t)t * 128;
        #pragma unroll
        for (int c = 0; c < 4; ++c)
            GLD16(Abyte + goffA[c] + kb, la + c * 4096 + ldst);
        #pragma unroll
        for (int c = 0; c < 3; ++c)
            GLD16(Bbyte + goffB[c] + kb, lb + c * 4096 + ldst);
    };

    const int rl = lane & 15;
    const int kg = lane >> 4;
    const int rswz = (rl & 7) << 4;

    auto compute = [&](int buf) {
        const char* la = &lds[buf][0];
        const char* lb = &lds[buf][16384];
        #pragma unroll
        for (int ks = 0; ks < 2; ++ks) {
            bf16x8 av[4], bvv[3];
            #pragma unroll
            for (int m = 0; m < 4; ++m) {
                const int row = wr * 64 + m * 16 + rl;
                const int addr = (row * 128 + ks * 64 + kg * 16) ^ rswz;
                av[m] = *(const bf16x8*)(la + addr);
            }
            #pragma unroll
            for (int n = 0; n < 3; ++n) {
                const int row = wc * 48 + n * 16 + rl;
                const int addr = (row * 128 + ks * 64 + kg * 16) ^ rswz;
                bvv[n] = *(const bf16x8*)(lb + addr);
            }
            #pragma unroll
            for (int m = 0; m < 4; ++m)
                #pragma unroll
                for (int n = 0; n < 3; ++n)
                    acc[m][n] = __builtin_amdgcn_mfma_f32_16x16x32_bf16(
                        av[m], bvv[n], acc[m][n], 0, 0, 0);
        }
    };

    stage(0, 0);
    __syncthreads();
    const int NT = KEFF / 64;   // 24
    for (int t = 0; t < NT; ++t) {
        if (t + 1 < NT) stage((t + 1) & 1, t + 1);
        compute(t & 1);
        __syncthreads();
    }

    // --- epilogue: bias + store (16-col frag never straddles a 512 boundary)
    #pragma unroll
    for (int n = 0; n < 3; ++n) {
        const int cabs = col0 + wc * 48 + n * 16 + rl;
        const int which = cabs >> 9;
        const int cl = cabs & 511;
        const float* bias = which == 0 ? bq : (which == 1 ? bk : bv);
        float* outp = which == 0 ? qo : (which == 1 ? ko : vo);
        const float bs = bias[cl];
        #pragma unroll
        for (int m = 0; m < 4; ++m) {
            const int rb = row0 + wr * 64 + m * 16 + kg * 4;
            #pragma unroll
            for (int r = 0; r < 4; ++r)
                outp[(size_t)(rb + r) * DIMSZ + cl] = acc[m][n][r] + bs;
        }
    }
}

// ---------------------------------------------------------------------------
// chunk_kv: KV_c[d,e] = sum_j lambda_d^{C-1-j} k[j,d] v[j,e]
// ---------------------------------------------------------------------------
__global__ __launch_bounds__(256) void chunk_kv_kernel(
    const float* __restrict__ k, const float* __restrict__ v,
    const float* __restrict__ theta, const float* __restrict__ logamp,
    float2* __restrict__ kv)
{
    const int bhc = blockIdx.x;
    const int c  = bhc & (NC - 1);
    const int bh = bhc >> 4;
    const int b = bh >> 3, h = bh & 7;
    const int tid = threadIdx.x;
    const int lane = tid & 63, grp = tid >> 6;

    __shared__ float ktr[CHUNK][ND + 1];
    __shared__ float kti[CHUNK][ND + 1];
    __shared__ float vs[CHUNK][ND + 1];

    const float th = theta[h*ND + lane];
    const float la = logamp[h];

    for (int jj = 0; jj < 16; ++jj) {
        const int j = grp*16 + jj;
        const int l = c*CHUNK + j;
        const size_t off = ((size_t)(b*L_SEQ + l)) * DIMSZ + h*ND + lane;
        const float kk = k[off];
        const float vv = v[off];
        const float p = (float)(CHUNK - 1 - j);
        const float ap = expf(la * p);
        float s, ct; sincosf(th * p, &s, &ct);
        ktr[j][lane] = kk * ap * ct;
        kti[j][lane] = kk * ap * s;
        vs[j][lane]  = vv;
    }
    __syncthreads();

    float accr[16], acci[16];
    #pragma unroll
    for (int dd = 0; dd < 16; ++dd) { accr[dd] = 0.f; acci[dd] = 0.f; }
    for (int j = 0; j < CHUNK; ++j) {
        const float vv = vs[j][lane];
        #pragma unroll
        for (int dd = 0; dd < 16; ++dd) {
            const int d = grp*16 + dd;
            accr[dd] = fmaf(ktr[j][d], vv, accr[dd]);
            acci[dd] = fmaf(kti[j][d], vv, acci[dd]);
        }
    }
    float2* dst = kv + (size_t)bhc * (ND*ND);
    #pragma unroll
    for (int dd = 0; dd < 16; ++dd) {
        const int d = grp*16 + dd;
        dst[d*ND + lane] = make_float2(accr[dd], acci[dd]);
    }
}

// ---------------------------------------------------------------------------
// scan: kvB[bh][c] := state BEFORE chunk c.  B_0 = last_conv.
// All 16 chunk loads prefetched before the dependent chain.
// ---------------------------------------------------------------------------
__global__ __launch_bounds__(256) void scan_kernel(
    float2* __restrict__ kvB,
    const float* __restrict__ lc_re, const float* __restrict__ lc_im,
    const float* __restrict__ theta, const float* __restrict__ logamp)
{
    const int gid = blockIdx.x * 256 + threadIdx.x;   // 65536
    const int bh = gid >> 12;
    const int idx = gid & 4095;
    const int h = bh & 7;
    const int d = idx >> 6;

    const float th = theta[h*ND + d];
    const float la = logamp[h];
    const float ampC = expf(la * (float)CHUNK);
    float s, ct; sincosf(th * (float)CHUNK, &s, &ct);
    const float aCr = ampC * ct, aCi = ampC * s;

    float2* base = kvB + (size_t)bh * NC * (ND*ND) + idx;

    float2 t[NC];
    #pragma unroll
    for (int c = 0; c < NC; ++c) t[c] = base[(size_t)c * (ND*ND)];

    float Sr = lc_re[h*ND*ND + idx];
    float Si = lc_im[h*ND*ND + idx];
    #pragma unroll
    for (int c = 0; c < NC; ++c) {
        base[(size_t)c * (ND*ND)] = make_float2(Sr, Si);
        const float nr = aCr*Sr - aCi*Si + t[c].x;
        const float ni = aCr*Si + aCi*Sr + t[c].y;
        Sr = nr; Si = ni;
    }
}

// ---------------------------------------------------------------------------
// chunk_out: cross term + masked intra-chunk attention.
// 512 blocks: blockIdx.x = bhc*2 + half; each block does 32 output rows.
// ---------------------------------------------------------------------------
__global__ __launch_bounds__(256) void chunk_out_kernel(
    const float* __restrict__ q, const float* __restrict__ k, const float* __restrict__ v,
    const float2* __restrict__ Bst,
    const float* __restrict__ theta, const float* __restrict__ logamp,
    float* __restrict__ out)
{
    const int half = blockIdx.x & 1;
    const int bhc = blockIdx.x >> 1;
    const int c  = bhc & (NC - 1);
    const int bh = bhc >> 4;
    const int b = bh >> 3, h = bh & 7;
    const int tid = threadIdx.x;
    const int lane = tid & 63, grp = tid >> 6;
    const int ty = tid >> 4, tx = tid & 15;   // thread tile: 2 rows x 4 cols

    __shared__ float QR[32][ND + 1];
    __shared__ float QI[32][ND + 1];
    __shared__ float KR[CHUNK][ND + 1];
    __shared__ float KI[CHUNK][ND + 1];
    __shared__ float VS[CHUNK][ND + 1];
    __shared__ float cth[ND], sth[ND];

    const float la = logamp[h];
    {
        const float th = theta[h*ND + lane];
        if (tid < ND) { float s0, c0; sincosf(th, &s0, &c0); cth[tid] = c0; sth[tid] = s0; }
        // Q: 32 rows (this half)
        #pragma unroll
        for (int jj = 0; jj < 8; ++jj) {
            const int jl = grp*8 + jj;
            const int jabs = half*32 + jl;
            const int l = c*CHUNK + jabs;
            const size_t off = ((size_t)(b*L_SEQ + l)) * DIMSZ + h*ND + lane;
            const float qq = q[off];
            float s, cc; sincosf(th * (float)jabs, &s, &cc);
            QR[jl][lane] = qq * cc; QI[jl][lane] = qq * s;
        }
        // K, V: full chunk
        #pragma unroll
        for (int jj = 0; jj < 16; ++jj) {
            const int j = grp*16 + jj;
            const int l = c*CHUNK + j;
            const size_t off = ((size_t)(b*L_SEQ + l)) * DIMSZ + h*ND + lane;
            const float kk = k[off], vv = v[off];
            float s, cc; sincosf(th * (float)j, &s, &cc);
            KR[j][lane] = kk * cc; KI[j][lane] = kk * s;
            VS[j][lane] = vv;
        }
    }
    __syncthreads();

    float accO[2][4] = {};

    // ---- cross term ----
    float ampj1[2];
    #pragma unroll
    for (int i = 0; i < 2; ++i) ampj1[i] = expf(la * (float)(half*32 + ty*2 + i + 1));
    const float2* Bbase = Bst + (size_t)bhc * (ND*ND);
    for (int d = 0; d < ND; ++d) {
        const float cd = cth[d], sd = sth[d];
        float2 Bv[4];
        #pragma unroll
        for (int u = 0; u < 4; ++u) Bv[u] = Bbase[d*ND + tx*4 + u];
        #pragma unroll
        for (int i = 0; i < 2; ++i) {
            const float qr = QR[ty*2+i][d], qi = QI[ty*2+i][d];
            const float qcr = (qr*cd - qi*sd) * ampj1[i];
            const float qci = (qr*sd + qi*cd) * ampj1[i];
            #pragma unroll
            for (int u = 0; u < 4; ++u)
                accO[i][u] = fmaf(qcr, Bv[u].x, fmaf(-qci, Bv[u].y, accO[i][u]));
        }
    }

    // ---- intra scores A[jl, jp] (32 x 64) ----
    float accA[2][4] = {};
    for (int d = 0; d < ND; ++d) {
        float qrv[2], qiv[2], krv[4], kiv[4];
        #pragma unroll
        for (int i = 0; i < 2; ++i) { qrv[i] = QR[ty*2+i][d]; qiv[i] = QI[ty*2+i][d]; }
        #pragma unroll
        for (int u = 0; u < 4; ++u) { krv[u] = KR[tx*4+u][d]; kiv[u] = KI[tx*4+u][d]; }
        #pragma unroll
        for (int i = 0; i < 2; ++i)
            #pragma unroll
            for (int u = 0; u < 4; ++u)
                accA[i][u] = fmaf(qrv[i], krv[u], fmaf(qiv[i], kiv[u], accA[i][u]));
    }
    __syncthreads();
    float (*SA)[ND + 1] = KR;   // reuse KR rows 0..31 for masked scores
    #pragma unroll
    for (int i = 0; i < 2; ++i) {
        const int jl = ty*2 + i;
        const int jabs = half*32 + jl;
        #pragma unroll
        for (int u = 0; u < 4; ++u) {
            const int jp = tx*4 + u;
            const int delta = jabs - jp;
            SA[jl][jp] = (delta >= 0) ? accA[i][u] * expf(la * (float)delta) : 0.0f;
        }
    }
    __syncthreads();

    // ---- PV ----
    const int jpmax = half*32 + 32;
    for (int jp = 0; jp < jpmax; ++jp) {
        float av[2], vv[4];
        #pragma unroll
        for (int i = 0; i < 2; ++i) av[i] = SA[ty*2+i][jp];
        #pragma unroll
        for (int u = 0; u < 4; ++u) vv[u] = VS[jp][tx*4+u];
        #pragma unroll
        for (int i = 0; i < 2; ++i)
            #pragma unroll
            for (int u = 0; u < 4; ++u)
                accO[i][u] = fmaf(av[i], vv[u], accO[i][u]);
    }

    #pragma unroll
    for (int i = 0; i < 2; ++i) {
        const int l = c*CHUNK + half*32 + ty*2 + i;
        const size_t off = ((size_t)(b*L_SEQ + l)) * DIMSZ + h*ND + tx*4;
        *(float4*)(out + off) = make_float4(accO[i][0], accO[i][1], accO[i][2], accO[i][3]);
    }
}

// ---------------------------------------------------------------------------
extern "C" void kernel_launch(void* const* d_in, const int* in_sizes, int n_in,
                              void* d_out, int out_size, void* d_ws, size_t ws_size,
                              hipStream_t stream)
{
    const float* x     = (const float*)d_in[0];
    const float* wq_w  = (const float*)d_in[1];
    const float* wq_b  = (const float*)d_in[2];
    const float* wk_w  = (const float*)d_in[3];
    const float* wk_b  = (const float*)d_in[4];
    const float* wv_w  = (const float*)d_in[5];
    const float* wv_b  = (const float*)d_in[6];
    const float* ph_re = (const float*)d_in[7];
    const float* ph_im = (const float*)d_in[8];
    const float* ampl  = (const float*)d_in[9];
    const float* lc_re = (const float*)d_in[10];
    const float* lc_im = (const float*)d_in[11];
    float* out = (float*)d_out;

    float* wsf = (float*)d_ws;
    const size_t qkv_sz = (size_t)NB * L_SEQ * DIMSZ;       // 1,048,576 floats
    float* q = wsf;
    float* k = q + qkv_sz;
    float* v = k + qkv_sz;
    float* theta  = v + qkv_sz;                              // 512 floats
    float* logamp = theta + 512;                             // 512 floats (pad)
    unsigned short* Apk = (unsigned short*)(logamp + 512);   // 2048*1536 bf16 = 6MB
    float2* kvB = (float2*)(Apk + (size_t)MTOT * KEFF);      // 8MB
    unsigned short* Bpk = (unsigned short*)kvB;              // alias (4.7MB, dead before chunk_kv)

    pack_all_kernel<<<1793, 256, 0, stream>>>(
        x, wq_w, wk_w, wv_w, ph_re, ph_im, ampl, Apk, Bpk, theta, logamp);
    gemm_kernel<<<dim3(MTOT / BM, NTOT / BN), 256, 0, stream>>>(
        Apk, Bpk, wq_b, wk_b, wv_b, q, k, v);
    chunk_kv_kernel<<<BHTOT * NC, 256, 0, stream>>>(k, v, theta, logamp, kvB);
    scan_kernel<<<(BHTOT * ND * ND) / 256, 256, 0, stream>>>(kvB, lc_re, lc_im, theta, logamp);
    chunk_out_kernel<<<BHTOT * NC * 2, 256, 0, stream>>>(q, k, v, kvB, theta, logamp, out);
}